// Round 4
// baseline (772.807 us; speedup 1.0000x reference)
//
#include <hip/hip_runtime.h>

namespace {

constexpr int BATCH = 32768;
constexpr int STEPS = 20;
constexpr int WD    = 48;
constexpr int WAVES = 4;           // waves per block
constexpr int IPW   = WD / WAVES;  // 12 output units per wave
constexpr int CH    = 4;           // k-chunk size (float4s read per chunk)
constexpr int NCH   = WD / CH;     // 12 chunks
constexpr float LR   = 0.1f;
constexpr float B1C  = 0.9f;
constexpr float B2C  = 0.999f;
constexpr float AEPS = 1e-8f;

__device__ __forceinline__ void swish3(float z, float& a, float& d1, float& d2) {
    const float sg = 1.f / (1.f + __expf(-z));
    const float sp = sg * (1.f - sg);
    d1 = fmaf(z, sp, sg);                      // swish'
    d2 = sp * fmaf(z, 1.f - 2.f * sg, 2.f);    // swish''
    a  = z * sg;
}

// Sample-per-lane; 4 waves split 48 units (12 each). Weights wave-uniform ->
// SGPR. Activations stream LDS->reg in chunks of 4 so nothing big is live
// across barriers (R3 spilled 144 floats; this keeps peak ~36+16 regs).
__global__ __launch_bounds__(256, 2) void ebm_kernel(
    const float* __restrict__ x_in,  const float* __restrict__ eps_in,
    const float* __restrict__ W1,    const float* __restrict__ b1,
    const float* __restrict__ W2,    const float* __restrict__ b2,
    const float* __restrict__ W3,    const float* __restrict__ b3,
    const float* __restrict__ W4,
    float* __restrict__ out)
{
    const int lane = threadIdx.x & 63;
    const int wid  = __builtin_amdgcn_readfirstlane(threadIdx.x >> 6);
    const int s    = blockIdx.x * 64 + lane;

    __shared__ float4 actS[WD][64];         // (a, a', a'', pad)
    __shared__ float2 pdS[2][WAVES][64];    // parity ping-pong partials

    const float xv = x_in[s];
    float y = 0.f, m = 0.f, v = 0.f;
    float pb1 = 1.f, pb2 = 1.f;

    for (int t = 0; t < STEPS; ++t) {
        const float e  = eps_in[t * BATCH + s];
        const float y0 = y + e;
        const int   pp = t & 1;
        pb1 *= B1C; pb2 *= B2C;

        // ---- layer 1 (2 -> 48): this wave's 12 units ----
#pragma unroll
        for (int ii = 0; ii < IPW; ++ii) {
            const int i = wid * IPW + ii;
            const float w1x = W1[2 * i];
            const float w1y = W1[2 * i + 1];
            const float z = fmaf(w1y, y0, fmaf(w1x, xv, b1[i]));
            float a, d1, d2; swish3(z, a, d1, d2);
            actS[i][lane] = make_float4(a, d1 * w1y, d2 * w1y * w1y, 0.f);
        }
        __syncthreads();                     // L1 outputs visible

        // ---- layer 2 (48 -> 48): chunked LDS streaming ----
        float z[IPW], zp[IPW], zq[IPW];
#pragma unroll
        for (int ii = 0; ii < IPW; ++ii) {
            z[ii] = b2[wid * IPW + ii]; zp[ii] = 0.f; zq[ii] = 0.f;
        }
#pragma unroll
        for (int kc = 0; kc < NCH; ++kc) {
            const float4 c0 = actS[kc * CH + 0][lane];
            const float4 c1 = actS[kc * CH + 1][lane];
            const float4 c2 = actS[kc * CH + 2][lane];
            const float4 c3 = actS[kc * CH + 3][lane];
#pragma unroll
            for (int ii = 0; ii < IPW; ++ii) {
                const int i = wid * IPW + ii;
                const float w0 = W2[i * WD + kc * CH + 0];
                const float w1 = W2[i * WD + kc * CH + 1];
                const float w2 = W2[i * WD + kc * CH + 2];
                const float w3 = W2[i * WD + kc * CH + 3];
                z[ii]  = fmaf(w0, c0.x, z[ii]);  zp[ii] = fmaf(w0, c0.y, zp[ii]);  zq[ii] = fmaf(w0, c0.z, zq[ii]);
                z[ii]  = fmaf(w1, c1.x, z[ii]);  zp[ii] = fmaf(w1, c1.y, zp[ii]);  zq[ii] = fmaf(w1, c1.z, zq[ii]);
                z[ii]  = fmaf(w2, c2.x, z[ii]);  zp[ii] = fmaf(w2, c2.y, zp[ii]);  zq[ii] = fmaf(w2, c2.z, zq[ii]);
                z[ii]  = fmaf(w3, c3.x, z[ii]);  zp[ii] = fmaf(w3, c3.y, zp[ii]);  zq[ii] = fmaf(w3, c3.z, zq[ii]);
            }
        }
        __syncthreads();                     // all actS reads done

#pragma unroll
        for (int ii = 0; ii < IPW; ++ii) {
            const int i = wid * IPW + ii;
            float a, d1, d2; swish3(z[ii], a, d1, d2);
            actS[i][lane] = make_float4(a, d1 * zp[ii],
                                        fmaf(d2 * zp[ii], zp[ii], d1 * zq[ii]), 0.f);
        }
        __syncthreads();                     // L2 outputs visible

        // ---- layer 3 (48 -> 48) + W4 dot, chunked ----
#pragma unroll
        for (int ii = 0; ii < IPW; ++ii) {
            z[ii] = b3[wid * IPW + ii]; zp[ii] = 0.f; zq[ii] = 0.f;
        }
#pragma unroll
        for (int kc = 0; kc < NCH; ++kc) {
            const float4 c0 = actS[kc * CH + 0][lane];
            const float4 c1 = actS[kc * CH + 1][lane];
            const float4 c2 = actS[kc * CH + 2][lane];
            const float4 c3 = actS[kc * CH + 3][lane];
#pragma unroll
            for (int ii = 0; ii < IPW; ++ii) {
                const int i = wid * IPW + ii;
                const float w0 = W3[i * WD + kc * CH + 0];
                const float w1 = W3[i * WD + kc * CH + 1];
                const float w2 = W3[i * WD + kc * CH + 2];
                const float w3 = W3[i * WD + kc * CH + 3];
                z[ii]  = fmaf(w0, c0.x, z[ii]);  zp[ii] = fmaf(w0, c0.y, zp[ii]);  zq[ii] = fmaf(w0, c0.z, zq[ii]);
                z[ii]  = fmaf(w1, c1.x, z[ii]);  zp[ii] = fmaf(w1, c1.y, zp[ii]);  zq[ii] = fmaf(w1, c1.z, zq[ii]);
                z[ii]  = fmaf(w2, c2.x, z[ii]);  zp[ii] = fmaf(w2, c2.y, zp[ii]);  zq[ii] = fmaf(w2, c2.z, zq[ii]);
                z[ii]  = fmaf(w3, c3.x, z[ii]);  zp[ii] = fmaf(w3, c3.y, zp[ii]);  zq[ii] = fmaf(w3, c3.z, zq[ii]);
            }
        }

        float pd1 = 0.f, pd2 = 0.f;
#pragma unroll
        for (int ii = 0; ii < IPW; ++ii) {
            const int i = wid * IPW + ii;
            float a, d1, d2; swish3(z[ii], a, d1, d2);
            const float w4 = W4[i];
            pd1 = fmaf(w4, d1 * zp[ii], pd1);
            pd2 = fmaf(w4, fmaf(d2 * zp[ii], zp[ii], d1 * zq[ii]), pd2);
        }
        pdS[pp][wid][lane] = make_float2(pd1, pd2);
        __syncthreads();                     // partials visible; also guards
                                             // actS WAR for next step's L1

        float g1 = 0.f, g2 = 0.f;
#pragma unroll
        for (int w = 0; w < WAVES; ++w) {
            const float2 p = pdS[pp][w][lane];
            g1 += p.x; g2 += p.y;
        }
        // g = E'(y0) + E''(y0)*(y - y0) = E' - e*E''
        const float g = fmaf(g2, -e, g1);

        // Adam (replicated identically in all waves)
        m = fmaf(B1C, m, (1.f - B1C) * g);
        v = fmaf(B2C, v, (1.f - B2C) * g * g);
        const float mh = m / (1.f - pb1);
        const float vh = v / (1.f - pb2);
        y -= LR * mh / (sqrtf(vh) + AEPS);
        // no end-of-step barrier: pdS is parity double-buffered, actS WAR is
        // covered by the post-pdS barrier above.
    }

    if (wid == 0) out[s] = y;
}

} // namespace

extern "C" void kernel_launch(void* const* d_in, const int* in_sizes, int n_in,
                              void* d_out, int out_size, void* d_ws, size_t ws_size,
                              hipStream_t stream) {
    const float* x   = (const float*)d_in[0];
    const float* eps = (const float*)d_in[1];
    const float* W1  = (const float*)d_in[2];
    const float* b1  = (const float*)d_in[3];
    const float* W2  = (const float*)d_in[4];
    const float* b2  = (const float*)d_in[5];
    const float* W3  = (const float*)d_in[6];
    const float* b3  = (const float*)d_in[7];
    const float* W4  = (const float*)d_in[8];
    float* out = (float*)d_out;

    ebm_kernel<<<BATCH / 64, 64 * WAVES, 0, stream>>>(x, eps, W1, b1, W2, b2, W3, b3, W4, out);
}

// Round 5
// 498.527 us; speedup vs baseline: 1.5502x; 1.5502x over previous
//
#include <hip/hip_runtime.h>

namespace {

constexpr int BATCH = 32768;
constexpr int STEPS = 20;
constexpr int WD    = 48;
constexpr int WAVES = 4;           // waves per block
constexpr int IPW   = WD / WAVES;  // 12 output units per wave
constexpr int NCH   = WD / 4;      // 12 chunks of 4 k-values
constexpr float LR   = 0.1f;
constexpr float B1C  = 0.9f;
constexpr float B2C  = 0.999f;
constexpr float AEPS = 1e-8f;

__device__ __forceinline__ void swish3(float z, float& a, float& d1, float& d2) {
    const float sg = 1.f / (1.f + __expf(-z));
    const float sp = sg * (1.f - sg);
    d1 = fmaf(z, sp, sg);                      // swish'
    d2 = sp * fmaf(z, 1.f - 2.f * sg, 2.f);    // swish''
    a  = z * sg;
}

// Sample-per-lane; 4 waves x 12 units. Weight pointers are laundered through
// an empty asm into VGPRs so weight loads stay VECTOR (VMEM/L1) instead of
// being scalarized+hoisted into an SGPR-spill storm (R4's 21MB scratch).
__global__ __launch_bounds__(256, 2) void ebm_kernel(
    const float* __restrict__ x_in,  const float* __restrict__ eps_in,
    const float* __restrict__ W1,    const float* __restrict__ b1,
    const float* __restrict__ W2,    const float* __restrict__ b2,
    const float* __restrict__ W3,    const float* __restrict__ b3,
    const float* __restrict__ W4,
    float* __restrict__ out)
{
    const int lane = threadIdx.x & 63;
    const int wid  = __builtin_amdgcn_readfirstlane(threadIdx.x >> 6);
    const int s    = blockIdx.x * 64 + lane;

    __shared__ float4 actS[WD][64];         // (a, a', a'', pad)
    __shared__ float2 pdS[2][WAVES][64];    // parity ping-pong partials

    // Launder: break uniformity proof -> vector loads, no SGPR pressure.
    const float4* W2v = reinterpret_cast<const float4*>(W2);
    const float4* W3v = reinterpret_cast<const float4*>(W3);
    asm("" : "+v"(W2v));
    asm("" : "+v"(W3v));

    const float xv = x_in[s];
    float y = 0.f, m = 0.f, v = 0.f;
    float pb1 = 1.f, pb2 = 1.f;

    for (int t = 0; t < STEPS; ++t) {
        const float e  = eps_in[t * BATCH + s];
        const float y0 = y + e;
        const int   pp = t & 1;
        pb1 *= B1C; pb2 *= B2C;

        // ---- layer 1 (2 -> 48): this wave's 12 units ----
#pragma unroll
        for (int ii = 0; ii < IPW; ++ii) {
            const int i = wid * IPW + ii;
            const float w1x = W1[2 * i];
            const float w1y = W1[2 * i + 1];
            const float z1 = fmaf(w1y, y0, fmaf(w1x, xv, b1[i]));
            float a, d1, d2; swish3(z1, a, d1, d2);
            actS[i][lane] = make_float4(a, d1 * w1y, d2 * w1y * w1y, 0.f);
        }
        __syncthreads();                     // L1 outputs visible

        // ---- layer 2 (48 -> 48): chunked LDS streaming, vector weights ----
        float z[IPW], zp[IPW], zq[IPW];
#pragma unroll
        for (int ii = 0; ii < IPW; ++ii) {
            z[ii] = b2[wid * IPW + ii]; zp[ii] = 0.f; zq[ii] = 0.f;
        }
#pragma unroll 2
        for (int kc = 0; kc < NCH; ++kc) {
            const float4 c0 = actS[kc * 4 + 0][lane];
            const float4 c1 = actS[kc * 4 + 1][lane];
            const float4 c2 = actS[kc * 4 + 2][lane];
            const float4 c3 = actS[kc * 4 + 3][lane];
#pragma unroll
            for (int ii = 0; ii < IPW; ++ii) {
                const float4 w4v = W2v[(wid * IPW + ii) * NCH + kc];
                z[ii]  = fmaf(w4v.x, c0.x, z[ii]);  zp[ii] = fmaf(w4v.x, c0.y, zp[ii]);  zq[ii] = fmaf(w4v.x, c0.z, zq[ii]);
                z[ii]  = fmaf(w4v.y, c1.x, z[ii]);  zp[ii] = fmaf(w4v.y, c1.y, zp[ii]);  zq[ii] = fmaf(w4v.y, c1.z, zq[ii]);
                z[ii]  = fmaf(w4v.z, c2.x, z[ii]);  zp[ii] = fmaf(w4v.z, c2.y, zp[ii]);  zq[ii] = fmaf(w4v.z, c2.z, zq[ii]);
                z[ii]  = fmaf(w4v.w, c3.x, z[ii]);  zp[ii] = fmaf(w4v.w, c3.y, zp[ii]);  zq[ii] = fmaf(w4v.w, c3.z, zq[ii]);
            }
        }
        __syncthreads();                     // all actS reads done

#pragma unroll
        for (int ii = 0; ii < IPW; ++ii) {
            const int i = wid * IPW + ii;
            float a, d1, d2; swish3(z[ii], a, d1, d2);
            actS[i][lane] = make_float4(a, d1 * zp[ii],
                                        fmaf(d2 * zp[ii], zp[ii], d1 * zq[ii]), 0.f);
        }
        __syncthreads();                     // L2 outputs visible

        // ---- layer 3 (48 -> 48) + W4 dot ----
#pragma unroll
        for (int ii = 0; ii < IPW; ++ii) {
            z[ii] = b3[wid * IPW + ii]; zp[ii] = 0.f; zq[ii] = 0.f;
        }
#pragma unroll 2
        for (int kc = 0; kc < NCH; ++kc) {
            const float4 c0 = actS[kc * 4 + 0][lane];
            const float4 c1 = actS[kc * 4 + 1][lane];
            const float4 c2 = actS[kc * 4 + 2][lane];
            const float4 c3 = actS[kc * 4 + 3][lane];
#pragma unroll
            for (int ii = 0; ii < IPW; ++ii) {
                const float4 w4v = W3v[(wid * IPW + ii) * NCH + kc];
                z[ii]  = fmaf(w4v.x, c0.x, z[ii]);  zp[ii] = fmaf(w4v.x, c0.y, zp[ii]);  zq[ii] = fmaf(w4v.x, c0.z, zq[ii]);
                z[ii]  = fmaf(w4v.y, c1.x, z[ii]);  zp[ii] = fmaf(w4v.y, c1.y, zp[ii]);  zq[ii] = fmaf(w4v.y, c1.z, zq[ii]);
                z[ii]  = fmaf(w4v.z, c2.x, z[ii]);  zp[ii] = fmaf(w4v.z, c2.y, zp[ii]);  zq[ii] = fmaf(w4v.z, c2.z, zq[ii]);
                z[ii]  = fmaf(w4v.w, c3.x, z[ii]);  zp[ii] = fmaf(w4v.w, c3.y, zp[ii]);  zq[ii] = fmaf(w4v.w, c3.z, zq[ii]);
            }
        }

        float pd1 = 0.f, pd2 = 0.f;
#pragma unroll
        for (int ii = 0; ii < IPW; ++ii) {
            const int i = wid * IPW + ii;
            float a, d1, d2; swish3(z[ii], a, d1, d2);
            const float w4 = W4[i];
            pd1 = fmaf(w4, d1 * zp[ii], pd1);
            pd2 = fmaf(w4, fmaf(d2 * zp[ii], zp[ii], d1 * zq[ii]), pd2);
        }
        pdS[pp][wid][lane] = make_float2(pd1, pd2);
        __syncthreads();                     // partials visible; also actS WAR

        float g1 = 0.f, g2 = 0.f;
#pragma unroll
        for (int w = 0; w < WAVES; ++w) {
            const float2 p = pdS[pp][w][lane];
            g1 += p.x; g2 += p.y;
        }
        // g = E'(y0) + E''(y0)*(y - y0) = E' - e*E''
        const float g = fmaf(g2, -e, g1);

        // Adam (replicated identically in all waves)
        m = fmaf(B1C, m, (1.f - B1C) * g);
        v = fmaf(B2C, v, (1.f - B2C) * g * g);
        const float mh = m / (1.f - pb1);
        const float vh = v / (1.f - pb2);
        y -= LR * mh / (sqrtf(vh) + AEPS);
        // pdS is parity double-buffered; actS WAR covered by the barrier above.
    }

    if (wid == 0) out[s] = y;
}

} // namespace

extern "C" void kernel_launch(void* const* d_in, const int* in_sizes, int n_in,
                              void* d_out, int out_size, void* d_ws, size_t ws_size,
                              hipStream_t stream) {
    const float* x   = (const float*)d_in[0];
    const float* eps = (const float*)d_in[1];
    const float* W1  = (const float*)d_in[2];
    const float* b1  = (const float*)d_in[3];
    const float* W2  = (const float*)d_in[4];
    const float* b2  = (const float*)d_in[5];
    const float* W3  = (const float*)d_in[6];
    const float* b3  = (const float*)d_in[7];
    const float* W4  = (const float*)d_in[8];
    float* out = (float*)d_out;

    ebm_kernel<<<BATCH / 64, 64 * WAVES, 0, stream>>>(x, eps, W1, b1, W2, b2, W3, b3, W4, out);
}

// Round 6
// 479.235 us; speedup vs baseline: 1.6126x; 1.0403x over previous
//
#include <hip/hip_runtime.h>

namespace {

constexpr int BATCH = 32768;
constexpr int STEPS = 20;
constexpr int WD    = 48;
constexpr int WAVES = 8;           // waves per block
constexpr int IPW   = WD / WAVES;  // 6 output units per wave
constexpr int NCH   = WD / 4;      // 12 chunks of 4 k-values
constexpr float LR   = 0.1f;
constexpr float B1C  = 0.9f;
constexpr float B2C  = 0.999f;
constexpr float AEPS = 1e-8f;

__device__ __forceinline__ void swish3(float z, float& a, float& d1, float& d2) {
    const float sg = 1.f / (1.f + __expf(-z));
    const float sp = sg * (1.f - sg);
    d1 = fmaf(z, sp, sg);                      // swish'
    d2 = sp * fmaf(z, 1.f - 2.f * sg, 2.f);    // swish''
    a  = z * sg;
}

// 12 FMA-triples for one k-chunk against this wave's 6 units.
__device__ __forceinline__ void fma_clu(const float4* __restrict__ w,
                                        const float4& c0, const float4& c1,
                                        const float4& c2, const float4& c3,
                                        float* __restrict__ z,
                                        float* __restrict__ zp,
                                        float* __restrict__ zq) {
#pragma unroll
    for (int ii = 0; ii < IPW; ++ii) {
        z[ii]  = fmaf(w[ii].x, c0.x, z[ii]);
        zp[ii] = fmaf(w[ii].x, c0.y, zp[ii]);
        zq[ii] = fmaf(w[ii].x, c0.z, zq[ii]);
        z[ii]  = fmaf(w[ii].y, c1.x, z[ii]);
        zp[ii] = fmaf(w[ii].y, c1.y, zp[ii]);
        zq[ii] = fmaf(w[ii].y, c1.z, zq[ii]);
        z[ii]  = fmaf(w[ii].z, c2.x, z[ii]);
        zp[ii] = fmaf(w[ii].z, c2.y, zp[ii]);
        zq[ii] = fmaf(w[ii].z, c2.z, zq[ii]);
        z[ii]  = fmaf(w[ii].w, c3.x, z[ii]);
        zp[ii] = fmaf(w[ii].w, c3.y, zp[ii]);
        zq[ii] = fmaf(w[ii].w, c3.z, zq[ii]);
    }
}

// Full 48-k accumulation for this wave's 6 units, ping-pong weight prefetch.
// Wvw points at this wave's first unit row (float4 granularity).
__device__ __forceinline__ void layer_mm(const float4* __restrict__ Wvw,
                                         const float4 (*__restrict__ actS)[64],
                                         int lane,
                                         float* __restrict__ z,
                                         float* __restrict__ zp,
                                         float* __restrict__ zq) {
    float4 wA[IPW], wB[IPW];
#pragma unroll
    for (int ii = 0; ii < IPW; ++ii) wA[ii] = Wvw[ii * NCH + 0];
#pragma unroll 1
    for (int kc = 0; kc < NCH; kc += 2) {
        // prefetch kc+1 into wB
#pragma unroll
        for (int ii = 0; ii < IPW; ++ii) wB[ii] = Wvw[ii * NCH + kc + 1];
        {
            const float4 c0 = actS[kc * 4 + 0][lane];
            const float4 c1 = actS[kc * 4 + 1][lane];
            const float4 c2 = actS[kc * 4 + 2][lane];
            const float4 c3 = actS[kc * 4 + 3][lane];
            fma_clu(wA, c0, c1, c2, c3, z, zp, zq);
        }
        // prefetch kc+2 into wA (clamped; last pair's prefetch is dead)
        const int kn = (kc + 2 < NCH) ? kc + 2 : 0;
#pragma unroll
        for (int ii = 0; ii < IPW; ++ii) wA[ii] = Wvw[ii * NCH + kn];
        {
            const float4 c0 = actS[(kc + 1) * 4 + 0][lane];
            const float4 c1 = actS[(kc + 1) * 4 + 1][lane];
            const float4 c2 = actS[(kc + 1) * 4 + 2][lane];
            const float4 c3 = actS[(kc + 1) * 4 + 3][lane];
            fma_clu(wB, c0, c1, c2, c3, z, zp, zq);
        }
    }
}

// Sample-per-lane; 8 waves x 6 units; 4 waves/SIMD resident (2 blocks/CU).
// Weight pointers laundered to VGPRs -> vector loads (L1), no SGPR storm.
__global__ __launch_bounds__(512, 4) void ebm_kernel(
    const float* __restrict__ x_in,  const float* __restrict__ eps_in,
    const float* __restrict__ W1,    const float* __restrict__ b1,
    const float* __restrict__ W2,    const float* __restrict__ b2,
    const float* __restrict__ W3,    const float* __restrict__ b3,
    const float* __restrict__ W4,
    float* __restrict__ out)
{
    const int lane = threadIdx.x & 63;
    const int wid  = __builtin_amdgcn_readfirstlane(threadIdx.x >> 6);
    const int s    = blockIdx.x * 64 + lane;

    __shared__ float4 actS[WD][64];         // (a, a', a'', pad)
    __shared__ float2 pdS[2][WAVES][64];    // parity ping-pong partials

    // Launder: break uniformity proof -> vector loads, no SGPR pressure.
    const float4* W2v = reinterpret_cast<const float4*>(W2);
    const float4* W3v = reinterpret_cast<const float4*>(W3);
    asm("" : "+v"(W2v));
    asm("" : "+v"(W3v));
    const float4* W2w = W2v + (wid * IPW) * NCH;   // this wave's first row
    const float4* W3w = W3v + (wid * IPW) * NCH;

    const float xv = x_in[s];
    float y = 0.f, m = 0.f, v = 0.f;
    float pb1 = 1.f, pb2 = 1.f;

    for (int t = 0; t < STEPS; ++t) {
        const float e  = eps_in[t * BATCH + s];
        const float y0 = y + e;
        const int   pp = t & 1;
        pb1 *= B1C; pb2 *= B2C;

        // ---- layer 1 (2 -> 48): this wave's 6 units ----
#pragma unroll
        for (int ii = 0; ii < IPW; ++ii) {
            const int i = wid * IPW + ii;
            const float w1x = W1[2 * i];
            const float w1y = W1[2 * i + 1];
            const float z1 = fmaf(w1y, y0, fmaf(w1x, xv, b1[i]));
            float a, d1, d2; swish3(z1, a, d1, d2);
            actS[i][lane] = make_float4(a, d1 * w1y, d2 * w1y * w1y, 0.f);
        }
        __syncthreads();                     // L1 outputs visible

        // ---- layer 2 (48 -> 48) ----
        float z[IPW], zp[IPW], zq[IPW];
#pragma unroll
        for (int ii = 0; ii < IPW; ++ii) {
            z[ii] = b2[wid * IPW + ii]; zp[ii] = 0.f; zq[ii] = 0.f;
        }
        layer_mm(W2w, actS, lane, z, zp, zq);
        __syncthreads();                     // all actS reads done

#pragma unroll
        for (int ii = 0; ii < IPW; ++ii) {
            const int i = wid * IPW + ii;
            float a, d1, d2; swish3(z[ii], a, d1, d2);
            actS[i][lane] = make_float4(a, d1 * zp[ii],
                                        fmaf(d2 * zp[ii], zp[ii], d1 * zq[ii]), 0.f);
        }
        __syncthreads();                     // L2 outputs visible

        // ---- layer 3 (48 -> 48) + W4 dot ----
#pragma unroll
        for (int ii = 0; ii < IPW; ++ii) {
            z[ii] = b3[wid * IPW + ii]; zp[ii] = 0.f; zq[ii] = 0.f;
        }
        layer_mm(W3w, actS, lane, z, zp, zq);

        float pd1 = 0.f, pd2 = 0.f;
#pragma unroll
        for (int ii = 0; ii < IPW; ++ii) {
            const int i = wid * IPW + ii;
            float a, d1, d2; swish3(z[ii], a, d1, d2);
            const float w4 = W4[i];
            pd1 = fmaf(w4, d1 * zp[ii], pd1);
            pd2 = fmaf(w4, fmaf(d2 * zp[ii], zp[ii], d1 * zq[ii]), pd2);
        }
        pdS[pp][wid][lane] = make_float2(pd1, pd2);
        __syncthreads();                     // partials visible; also actS WAR

        float g1 = 0.f, g2 = 0.f;
#pragma unroll
        for (int w = 0; w < WAVES; ++w) {
            const float2 p = pdS[pp][w][lane];
            g1 += p.x; g2 += p.y;
        }
        // g = E'(y0) + E''(y0)*(y - y0) = E' - e*E''
        const float g = fmaf(g2, -e, g1);

        // Adam (replicated identically in all waves)
        m = fmaf(B1C, m, (1.f - B1C) * g);
        v = fmaf(B2C, v, (1.f - B2C) * g * g);
        const float mh = m / (1.f - pb1);
        const float vh = v / (1.f - pb2);
        y -= LR * mh / (sqrtf(vh) + AEPS);
        // pdS is parity double-buffered; actS WAR covered by the barrier above.
    }

    if (wid == 0) out[s] = y;
}

} // namespace

extern "C" void kernel_launch(void* const* d_in, const int* in_sizes, int n_in,
                              void* d_out, int out_size, void* d_ws, size_t ws_size,
                              hipStream_t stream) {
    const float* x   = (const float*)d_in[0];
    const float* eps = (const float*)d_in[1];
    const float* W1  = (const float*)d_in[2];
    const float* b1  = (const float*)d_in[3];
    const float* W2  = (const float*)d_in[4];
    const float* b2  = (const float*)d_in[5];
    const float* W3  = (const float*)d_in[6];
    const float* b3  = (const float*)d_in[7];
    const float* W4  = (const float*)d_in[8];
    float* out = (float*)d_out;

    ebm_kernel<<<BATCH / 64, 64 * WAVES, 0, stream>>>(x, eps, W1, b1, W2, b2, W3, b3, W4, out);
}

// Round 7
// 389.972 us; speedup vs baseline: 1.9817x; 1.2289x over previous
//
#include <hip/hip_runtime.h>

namespace {

constexpr int BATCH = 32768;
constexpr int STEPS = 20;
constexpr int WD    = 48;
constexpr int WAVES = 8;           // waves per block
constexpr int IPW   = WD / WAVES;  // 6 output units per wave
constexpr int NCH   = WD / 4;      // 12 k-chunks of 4
constexpr int ROW   = 52;          // padded row: 16B-aligned, bank-stride 20%32 (conflict-free)
constexpr float LR   = 0.1f;
constexpr float B1C  = 0.9f;
constexpr float B2C  = 0.999f;
constexpr float AEPS = 1e-8f;

__device__ __forceinline__ void swish3(float z, float& a, float& d1, float& d2) {
    const float sg = 1.f / (1.f + __expf(-z));
    const float sp = sg * (1.f - sg);
    d1 = fmaf(z, sp, sg);                      // swish'
    d2 = sp * fmaf(z, 1.f - 2.f * sg, 2.f);    // swish''
    a  = z * sg;
}

// Sample-per-lane; 8 waves x 6 units. Activations in transposed channel-split
// LDS (lane-major rows -> 3 b128 reads per 4-k chunk). Weights stay UNIFORM ->
// s_load_dwordx4 on the scalar pipe (rolled kc loop avoids R4's hoist storm).
__global__ __launch_bounds__(512, 4) void ebm_kernel(
    const float* __restrict__ x_in,  const float* __restrict__ eps_in,
    const float* __restrict__ W1,    const float* __restrict__ b1,
    const float* __restrict__ W2,    const float* __restrict__ b2,
    const float* __restrict__ W3,    const float* __restrict__ b3,
    const float* __restrict__ W4,
    float* __restrict__ out)
{
    const int lane = threadIdx.x & 63;
    const int wid  = __builtin_amdgcn_readfirstlane(threadIdx.x >> 6);
    const int s    = blockIdx.x * 64 + lane;
    const int u0   = wid * IPW;                 // first unit owned by this wave

    __shared__ float aV[64][ROW];               // value channel
    __shared__ float aP[64][ROW];               // d/dy channel
    __shared__ float aQ[64][ROW];               // d2/dy2 channel
    __shared__ float2 pdS[WAVES][64];           // per-wave (E', E'') partials

    const float4* __restrict__ W2v4 = reinterpret_cast<const float4*>(W2);
    const float4* __restrict__ W3v4 = reinterpret_cast<const float4*>(W3);

    const float xv = x_in[s];
    float y = 0.f, m = 0.f, v = 0.f;
    float pb1 = 1.f, pb2 = 1.f;

    for (int t = 0; t < STEPS; ++t) {
        const float e  = eps_in[t * BATCH + s];
        const float y0 = y + e;
        pb1 *= B1C; pb2 *= B2C;

        // ---- layer 1 (2 -> 48): this wave's 6 units ----
        float oa[IPW], op[IPW], oq[IPW];
#pragma unroll
        for (int ii = 0; ii < IPW; ++ii) {
            const int i = u0 + ii;
            const float w1x = W1[2 * i];
            const float w1y = W1[2 * i + 1];
            const float z1 = fmaf(w1y, y0, fmaf(w1x, xv, b1[i]));
            float a, d1, d2; swish3(z1, a, d1, d2);
            oa[ii] = a; op[ii] = d1 * w1y; oq[ii] = d2 * w1y * w1y;
        }
#pragma unroll
        for (int p = 0; p < IPW / 2; ++p) {
            *reinterpret_cast<float2*>(&aV[lane][u0 + 2 * p]) = make_float2(oa[2*p], oa[2*p+1]);
            *reinterpret_cast<float2*>(&aP[lane][u0 + 2 * p]) = make_float2(op[2*p], op[2*p+1]);
            *reinterpret_cast<float2*>(&aQ[lane][u0 + 2 * p]) = make_float2(oq[2*p], oq[2*p+1]);
        }
        __syncthreads();                         // b1: L1 acts visible

        // ---- layer 2 (48 -> 48): transposed reads, scalar weights ----
        float z[IPW], zp[IPW], zq[IPW];
#pragma unroll
        for (int ii = 0; ii < IPW; ++ii) {
            z[ii] = b2[u0 + ii]; zp[ii] = 0.f; zq[ii] = 0.f;
        }
#pragma unroll 1
        for (int kc = 0; kc < NCH; ++kc) {
            const float4 cv = *reinterpret_cast<const float4*>(&aV[lane][4 * kc]);
            const float4 cp = *reinterpret_cast<const float4*>(&aP[lane][4 * kc]);
            const float4 cq = *reinterpret_cast<const float4*>(&aQ[lane][4 * kc]);
#pragma unroll
            for (int ii = 0; ii < IPW; ++ii) {
                const float4 w = W2v4[(u0 + ii) * NCH + kc];   // uniform -> s_load_dwordx4
                z[ii]  = fmaf(w.x, cv.x, z[ii]);   zp[ii] = fmaf(w.x, cp.x, zp[ii]);   zq[ii] = fmaf(w.x, cq.x, zq[ii]);
                z[ii]  = fmaf(w.y, cv.y, z[ii]);   zp[ii] = fmaf(w.y, cp.y, zp[ii]);   zq[ii] = fmaf(w.y, cq.y, zq[ii]);
                z[ii]  = fmaf(w.z, cv.z, z[ii]);   zp[ii] = fmaf(w.z, cp.z, zp[ii]);   zq[ii] = fmaf(w.z, cq.z, zq[ii]);
                z[ii]  = fmaf(w.w, cv.w, z[ii]);   zp[ii] = fmaf(w.w, cp.w, zp[ii]);   zq[ii] = fmaf(w.w, cq.w, zq[ii]);
            }
        }
        __syncthreads();                         // b2: everyone's L1 reads done

#pragma unroll
        for (int ii = 0; ii < IPW; ++ii) {
            float a, d1, d2; swish3(z[ii], a, d1, d2);
            oa[ii] = a;
            op[ii] = d1 * zp[ii];
            oq[ii] = fmaf(d2 * zp[ii], zp[ii], d1 * zq[ii]);
        }
#pragma unroll
        for (int p = 0; p < IPW / 2; ++p) {
            *reinterpret_cast<float2*>(&aV[lane][u0 + 2 * p]) = make_float2(oa[2*p], oa[2*p+1]);
            *reinterpret_cast<float2*>(&aP[lane][u0 + 2 * p]) = make_float2(op[2*p], op[2*p+1]);
            *reinterpret_cast<float2*>(&aQ[lane][u0 + 2 * p]) = make_float2(oq[2*p], oq[2*p+1]);
        }
        __syncthreads();                         // b3: L2 acts visible

        // ---- layer 3 (48 -> 48) + W4 dot ----
#pragma unroll
        for (int ii = 0; ii < IPW; ++ii) {
            z[ii] = b3[u0 + ii]; zp[ii] = 0.f; zq[ii] = 0.f;
        }
#pragma unroll 1
        for (int kc = 0; kc < NCH; ++kc) {
            const float4 cv = *reinterpret_cast<const float4*>(&aV[lane][4 * kc]);
            const float4 cp = *reinterpret_cast<const float4*>(&aP[lane][4 * kc]);
            const float4 cq = *reinterpret_cast<const float4*>(&aQ[lane][4 * kc]);
#pragma unroll
            for (int ii = 0; ii < IPW; ++ii) {
                const float4 w = W3v4[(u0 + ii) * NCH + kc];
                z[ii]  = fmaf(w.x, cv.x, z[ii]);   zp[ii] = fmaf(w.x, cp.x, zp[ii]);   zq[ii] = fmaf(w.x, cq.x, zq[ii]);
                z[ii]  = fmaf(w.y, cv.y, z[ii]);   zp[ii] = fmaf(w.y, cp.y, zp[ii]);   zq[ii] = fmaf(w.y, cq.y, zq[ii]);
                z[ii]  = fmaf(w.z, cv.z, z[ii]);   zp[ii] = fmaf(w.z, cp.z, zp[ii]);   zq[ii] = fmaf(w.z, cq.z, zq[ii]);
                z[ii]  = fmaf(w.w, cv.w, z[ii]);   zp[ii] = fmaf(w.w, cp.w, zp[ii]);   zq[ii] = fmaf(w.w, cq.w, zq[ii]);
            }
        }

        float pd1 = 0.f, pd2 = 0.f;
#pragma unroll
        for (int ii = 0; ii < IPW; ++ii) {
            float a, d1, d2; swish3(z[ii], a, d1, d2);
            const float w4 = W4[u0 + ii];
            pd1 = fmaf(w4, d1 * zp[ii], pd1);
            pd2 = fmaf(w4, fmaf(d2 * zp[ii], zp[ii], d1 * zq[ii]), pd2);
        }
        pdS[wid][lane] = make_float2(pd1, pd2);
        __syncthreads();                         // b4: partials visible; guards
                                                 // act WAR for next step's L1

        float g1 = 0.f, g2 = 0.f;
#pragma unroll
        for (int w = 0; w < WAVES; ++w) {
            const float2 p = pdS[w][lane];
            g1 += p.x; g2 += p.y;
        }
        // g = E'(y0) + E''(y0)*(y - y0) = E' - e*E''
        const float g = fmaf(g2, -e, g1);

        // Adam (replicated identically in all waves)
        m = fmaf(B1C, m, (1.f - B1C) * g);
        v = fmaf(B2C, v, (1.f - B2C) * g * g);
        const float mh = m / (1.f - pb1);
        const float vh = v / (1.f - pb2);
        y -= LR * mh / (sqrtf(vh) + AEPS);
        // pdS WAR: next pd write is after next step's b1..b3 -> safe.
    }

    if (wid == 0) out[s] = y;
}

} // namespace

extern "C" void kernel_launch(void* const* d_in, const int* in_sizes, int n_in,
                              void* d_out, int out_size, void* d_ws, size_t ws_size,
                              hipStream_t stream) {
    const float* x   = (const float*)d_in[0];
    const float* eps = (const float*)d_in[1];
    const float* W1  = (const float*)d_in[2];
    const float* b1  = (const float*)d_in[3];
    const float* W2  = (const float*)d_in[4];
    const float* b2  = (const float*)d_in[5];
    const float* W3  = (const float*)d_in[6];
    const float* b3  = (const float*)d_in[7];
    const float* W4  = (const float*)d_in[8];
    float* out = (float*)d_out;

    ebm_kernel<<<BATCH / 64, 64 * WAVES, 0, stream>>>(x, eps, W1, b1, W2, b2, W3, b3, W4, out);
}

// Round 8
// 308.887 us; speedup vs baseline: 2.5019x; 1.2625x over previous
//
#include <hip/hip_runtime.h>

namespace {

typedef float f2 __attribute__((ext_vector_type(2)));

constexpr int BATCH = 32768;
constexpr int STEPS = 20;
constexpr int WD    = 48;
constexpr int WAVES = 12;          // waves per block
constexpr int IPW   = 4;           // units per wave == LDS chunk size
constexpr int NCH   = WD / 4;      // 12 chunks of 4 k-values
constexpr float LR   = 0.1f;
constexpr float B1C  = 0.9f;
constexpr float B2C  = 0.999f;
constexpr float AEPS = 1e-8f;

__device__ __forceinline__ void swish3(float z, float& a, float& d1, float& d2) {
    const float sg = 1.f / (1.f + __expf(-z));
    const float sp = sg * (1.f - sg);
    d1 = fmaf(z, sp, sg);                      // swish'
    d2 = sp * fmaf(z, 1.f - 2.f * sg, 2.f);    // swish''
    a  = z * sg;
}

// Sample-per-lane; 12 waves x 4 units (unit block == chunk). Chunk-major LDS:
// reads AND writes are canonical contiguous wave64 accesses (conflict-free,
// offset-immediate addressing). Weights uniform -> s_load on scalar pipe.
// Inner FMAs packed as float2 (even/odd k partials) -> v_pk_fma_f32.
__global__ __launch_bounds__(768, 6) void ebm_kernel(
    const float* __restrict__ x_in,  const float* __restrict__ eps_in,
    const float* __restrict__ W1,    const float* __restrict__ b1,
    const float* __restrict__ W2,    const float* __restrict__ b2,
    const float* __restrict__ W3,    const float* __restrict__ b3,
    const float* __restrict__ W4,
    float* __restrict__ out)
{
    const int lane = threadIdx.x & 63;
    const int wid  = __builtin_amdgcn_readfirstlane(threadIdx.x >> 6);
    const int s    = blockIdx.x * 64 + lane;
    const int u0   = wid * IPW;                 // first unit owned by this wave

    __shared__ float aV[NCH][64][4];            // value channel, chunk-major
    __shared__ float aP[NCH][64][4];            // d/dy
    __shared__ float aQ[NCH][64][4];            // d2/dy2
    __shared__ float2 pdS[WAVES][64];           // per-wave (E', E'') partials

    const float4* __restrict__ W2v4 = reinterpret_cast<const float4*>(W2);
    const float4* __restrict__ W3v4 = reinterpret_cast<const float4*>(W3);

    const float xv = x_in[s];
    float y = 0.f, m = 0.f, v = 0.f;
    float pb1 = 1.f, pb2 = 1.f;

    for (int t = 0; t < STEPS; ++t) {
        const float e  = eps_in[t * BATCH + s];
        const float y0 = y + e;
        pb1 *= B1C; pb2 *= B2C;

        // ---- layer 1 (2 -> 48): this wave's 4 units ----
        float oa[IPW], op[IPW], oq[IPW];
#pragma unroll
        for (int ii = 0; ii < IPW; ++ii) {
            const int i = u0 + ii;
            const float w1x = W1[2 * i];
            const float w1y = W1[2 * i + 1];
            const float z1 = fmaf(w1y, y0, fmaf(w1x, xv, b1[i]));
            float a, d1, d2; swish3(z1, a, d1, d2);
            oa[ii] = a; op[ii] = d1 * w1y; oq[ii] = d2 * w1y * w1y;
        }
        *reinterpret_cast<float4*>(aV[wid][lane]) = make_float4(oa[0], oa[1], oa[2], oa[3]);
        *reinterpret_cast<float4*>(aP[wid][lane]) = make_float4(op[0], op[1], op[2], op[3]);
        *reinterpret_cast<float4*>(aQ[wid][lane]) = make_float4(oq[0], oq[1], oq[2], oq[3]);
        __syncthreads();                         // b1: L1 acts visible

        // ---- layer 2 (48 -> 48): packed accumulation ----
        f2 az[IPW], ap2[IPW], aq2[IPW];
#pragma unroll
        for (int ii = 0; ii < IPW; ++ii) {
            az[ii]  = f2{b2[u0 + ii], 0.f};
            ap2[ii] = f2{0.f, 0.f};
            aq2[ii] = f2{0.f, 0.f};
        }
#pragma unroll 2
        for (int kc = 0; kc < NCH; ++kc) {
            const float4 cv = *reinterpret_cast<const float4*>(aV[kc][lane]);
            const float4 cp = *reinterpret_cast<const float4*>(aP[kc][lane]);
            const float4 cq = *reinterpret_cast<const float4*>(aQ[kc][lane]);
            const f2 cv01 = f2{cv.x, cv.y}, cv23 = f2{cv.z, cv.w};
            const f2 cp01 = f2{cp.x, cp.y}, cp23 = f2{cp.z, cp.w};
            const f2 cq01 = f2{cq.x, cq.y}, cq23 = f2{cq.z, cq.w};
#pragma unroll
            for (int ii = 0; ii < IPW; ++ii) {
                const float4 w = W2v4[(u0 + ii) * NCH + kc];   // uniform -> s_load
                const f2 w01 = f2{w.x, w.y}, w23 = f2{w.z, w.w};
                az[ii]  = __builtin_elementwise_fma(w01, cv01, az[ii]);
                az[ii]  = __builtin_elementwise_fma(w23, cv23, az[ii]);
                ap2[ii] = __builtin_elementwise_fma(w01, cp01, ap2[ii]);
                ap2[ii] = __builtin_elementwise_fma(w23, cp23, ap2[ii]);
                aq2[ii] = __builtin_elementwise_fma(w01, cq01, aq2[ii]);
                aq2[ii] = __builtin_elementwise_fma(w23, cq23, aq2[ii]);
            }
        }
        __syncthreads();                         // b2: all L1-act reads done

#pragma unroll
        for (int ii = 0; ii < IPW; ++ii) {
            const float z2 = az[ii].x + az[ii].y;
            const float zp = ap2[ii].x + ap2[ii].y;
            const float zq = aq2[ii].x + aq2[ii].y;
            float a, d1, d2; swish3(z2, a, d1, d2);
            oa[ii] = a;
            op[ii] = d1 * zp;
            oq[ii] = fmaf(d2 * zp, zp, d1 * zq);
        }
        *reinterpret_cast<float4*>(aV[wid][lane]) = make_float4(oa[0], oa[1], oa[2], oa[3]);
        *reinterpret_cast<float4*>(aP[wid][lane]) = make_float4(op[0], op[1], op[2], op[3]);
        *reinterpret_cast<float4*>(aQ[wid][lane]) = make_float4(oq[0], oq[1], oq[2], oq[3]);
        __syncthreads();                         // b3: L2 acts visible

        // ---- layer 3 (48 -> 48) + W4 dot ----
#pragma unroll
        for (int ii = 0; ii < IPW; ++ii) {
            az[ii]  = f2{b3[u0 + ii], 0.f};
            ap2[ii] = f2{0.f, 0.f};
            aq2[ii] = f2{0.f, 0.f};
        }
#pragma unroll 2
        for (int kc = 0; kc < NCH; ++kc) {
            const float4 cv = *reinterpret_cast<const float4*>(aV[kc][lane]);
            const float4 cp = *reinterpret_cast<const float4*>(aP[kc][lane]);
            const float4 cq = *reinterpret_cast<const float4*>(aQ[kc][lane]);
            const f2 cv01 = f2{cv.x, cv.y}, cv23 = f2{cv.z, cv.w};
            const f2 cp01 = f2{cp.x, cp.y}, cp23 = f2{cp.z, cp.w};
            const f2 cq01 = f2{cq.x, cq.y}, cq23 = f2{cq.z, cq.w};
#pragma unroll
            for (int ii = 0; ii < IPW; ++ii) {
                const float4 w = W3v4[(u0 + ii) * NCH + kc];
                const f2 w01 = f2{w.x, w.y}, w23 = f2{w.z, w.w};
                az[ii]  = __builtin_elementwise_fma(w01, cv01, az[ii]);
                az[ii]  = __builtin_elementwise_fma(w23, cv23, az[ii]);
                ap2[ii] = __builtin_elementwise_fma(w01, cp01, ap2[ii]);
                ap2[ii] = __builtin_elementwise_fma(w23, cp23, ap2[ii]);
                aq2[ii] = __builtin_elementwise_fma(w01, cq01, aq2[ii]);
                aq2[ii] = __builtin_elementwise_fma(w23, cq23, aq2[ii]);
            }
        }

        float pd1 = 0.f, pd2 = 0.f;
#pragma unroll
        for (int ii = 0; ii < IPW; ++ii) {
            const float z3 = az[ii].x + az[ii].y;
            const float zp = ap2[ii].x + ap2[ii].y;
            const float zq = aq2[ii].x + aq2[ii].y;
            float a, d1, d2; swish3(z3, a, d1, d2);
            const float w4 = W4[u0 + ii];
            pd1 = fmaf(w4, d1 * zp, pd1);
            pd2 = fmaf(w4, fmaf(d2 * zp, zp, d1 * zq), pd2);
        }
        pdS[wid][lane] = make_float2(pd1, pd2);
        __syncthreads();                         // b4: partials visible; also
                                                 // guards act WAR for next L1

        float g1 = 0.f, g2 = 0.f;
#pragma unroll
        for (int w = 0; w < WAVES; ++w) {
            const float2 p = pdS[w][lane];
            g1 += p.x; g2 += p.y;
        }
        // g = E'(y0) + E''(y0)*(y - y0) = E' - e*E''
        const float g = fmaf(g2, -e, g1);

        // Adam (replicated identically in all waves)
        m = fmaf(B1C, m, (1.f - B1C) * g);
        v = fmaf(B2C, v, (1.f - B2C) * g * g);
        const float mh = m / (1.f - pb1);
        const float vh = v / (1.f - pb2);
        y -= LR * mh / (sqrtf(vh) + AEPS);
        // pdS WAR: next pdS write is after next step's b1..b3 -> safe.
    }

    if (wid == 0) out[s] = y;
}

} // namespace

extern "C" void kernel_launch(void* const* d_in, const int* in_sizes, int n_in,
                              void* d_out, int out_size, void* d_ws, size_t ws_size,
                              hipStream_t stream) {
    const float* x   = (const float*)d_in[0];
    const float* eps = (const float*)d_in[1];
    const float* W1  = (const float*)d_in[2];
    const float* b1  = (const float*)d_in[3];
    const float* W2  = (const float*)d_in[4];
    const float* b2  = (const float*)d_in[5];
    const float* W3  = (const float*)d_in[6];
    const float* b3  = (const float*)d_in[7];
    const float* W4  = (const float*)d_in[8];
    float* out = (float*)d_out;

    ebm_kernel<<<BATCH / 64, 64 * WAVES, 0, stream>>>(x, eps, W1, b1, W2, b2, W3, b3, W4, out);
}